// Round 4
// baseline (77.008 us; speedup 1.0000x reference)
//
#include <hip/hip_runtime.h>

typedef __attribute__((ext_vector_type(8))) short bf16x8;
typedef __attribute__((ext_vector_type(4))) float f32x4;
typedef unsigned short u16;
typedef unsigned int u32;

constexpr int N = 8192;
constexpr int D = 128;
constexpr float CEXP   = 2.8853900817779268f;  // log2(e)/tau, tau = 0.5
constexpr float BSCALE = 1.6986435688113073f;  // sqrt(CEXP) folded into bf16 inputs

// ---------- fp32 -> bf16 (pre-scaled) ----------
__device__ __forceinline__ u16 f2bf(float x) {
  union { float f; unsigned u; } v;
  v.f = x;
  unsigned r = v.u + 0x7fffu + ((v.u >> 16) & 1u);  // RNE
  return (u16)(r >> 16);
}

__global__ void convert_kernel(const float4* __restrict__ z1, const float4* __restrict__ z2,
                               uint2* __restrict__ o1, uint2* __restrict__ o2) {
  int t = blockIdx.x * 256 + threadIdx.x;  // N*D/4 = 262144 float4s per matrix
  float4 a = z1[t];
  float4 b = z2[t];
  uint2 pa, pb;
  pa.x = (unsigned)f2bf(a.x * BSCALE) | ((unsigned)f2bf(a.y * BSCALE) << 16);
  pa.y = (unsigned)f2bf(a.z * BSCALE) | ((unsigned)f2bf(a.w * BSCALE) << 16);
  pb.x = (unsigned)f2bf(b.x * BSCALE) | ((unsigned)f2bf(b.y * BSCALE) << 16);
  pb.y = (unsigned)f2bf(b.z * BSCALE) | ((unsigned)f2bf(b.w * BSCALE) << 16);
  o1[t] = pa;
  o2[t] = pb;
}

// ---------- zero accumulators + output ----------
__global__ void zero_kernel(float* __restrict__ p, float* __restrict__ out) {
  int g = blockIdx.x * 256 + threadIdx.x;  // grid covers 3*N floats
  p[g] = 0.0f;
  if (g == 0) out[0] = 0.0f;
}

// ---------- async stage 16KB strip (64 rows x 256B): linear LDS dest, pre-swizzled src ----------
// swizzled layout: logical (row, chunk c) lives at byte row*256 + ((c ^ (row&15))<<4)
__device__ __forceinline__ void stage16k(char* lds, const char* gsrc, int soff, int doff) {
#pragma unroll
  for (int s = 0; s < 4; ++s) {
    __builtin_amdgcn_global_load_lds(
        (const __attribute__((address_space(1))) u32*)(gsrc + soff + s * 4096),
        (__attribute__((address_space(3))) u32*)(lds + doff + s * 4096), 16, 0, 0);
  }
}

// ---------- fused GEMM(z1_I x {z1,z2}_J^T) + exp + row/col sums ----------
// grid: 1024 = bi(64) x jg(16). jg<8: refl (B=z1 -> rowRefl); jg>=8: between (B=z2 -> rowBet+colBet).
// A (128 rows) staged once into B0+B1 and read to registers through the SAME swizzle formula
// as the B reads (k-permutation-safe); buffers then recycled for B double-buffering.
__global__ __launch_bounds__(256, 4) void gemm_kernel(const u16* __restrict__ z1b,
                                                      const u16* __restrict__ z2b,
                                                      float* __restrict__ rowRefl,
                                                      float* __restrict__ rowBet,
                                                      float* __restrict__ colBet) {
  __shared__ __align__(16) char B0[16384];
  __shared__ __align__(16) char B1[16384];
  const int tid = threadIdx.x;
  const int l = tid & 63, w = tid >> 6;
  const int lr = l & 15, lg = l >> 4;
  const int bi = blockIdx.x >> 4;
  const int jg = blockIdx.x & 15;
  const bool between = jg >= 8;
  const u16* bsrc = between ? z2b : z1b;
  const int j0 = (jg & 7) * 16;  // strips j0..j0+15, 64 rows each

  // staging offsets: linear LDS dest, inverse-swizzled global src (row&15 == tid>>4 for all s)
  const int soff = (tid >> 4) * 256 + (((tid & 15) ^ (tid >> 4)) << 4);
  const int doff = tid * 16;

  // ---- stage A tile (32KB) into B0 (rows 0-63) + B1 (rows 64-127), read to registers ----
  stage16k(B0, (const char*)(z1b + (size_t)bi * 128 * D), soff, doff);
  stage16k(B1, (const char*)(z1b + (size_t)(bi * 128 + 64) * D), soff, doff);
  __syncthreads();
  bf16x8 af[2][4];  // wave w owns A-rows w*32 .. w*32+31
  {
    const char* Asrc = (w & 2) ? B1 : B0;
    const int rbase = (w & 1) * 32 + lr;  // row within buffer; rbase&15 == lr
#pragma unroll
    for (int m = 0; m < 2; ++m)
#pragma unroll
      for (int kk = 0; kk < 4; ++kk)
        af[m][kk] = *(const bf16x8*)(Asrc + (rbase + m * 16) * 256 + (((kk * 4 + lg) ^ lr) << 4));
  }
  __syncthreads();  // all waves done reading A from B0/B1

  stage16k(B0, (const char*)(bsrc + (size_t)j0 * 64 * D), soff, doff);  // prologue strip 0

  float rowp[2][4];
#pragma unroll
  for (int m = 0; m < 2; ++m)
#pragma unroll
    for (int r = 0; r < 4; ++r) rowp[m][r] = 0.f;

  for (int t = 0; t < 16; ++t) {
    __syncthreads();  // strip t staged (vmcnt drained at barrier); prev readers done
    const char* cur = (t & 1) ? B1 : B0;
    char* nxt = (t & 1) ? B0 : B1;
    if (t + 1 < 16)
      stage16k(nxt, (const char*)(bsrc + (size_t)(j0 + t + 1) * 64 * D), soff, doff);

    f32x4 acc[2][4];
    const f32x4 z4 = {0.f, 0.f, 0.f, 0.f};
    {
      bf16x8 bfr[4];
#pragma unroll
      for (int n = 0; n < 4; ++n)
        bfr[n] = *(const bf16x8*)(cur + (n * 16 + lr) * 256 + ((lg ^ lr) << 4));
#pragma unroll
      for (int m = 0; m < 2; ++m)
#pragma unroll
        for (int n = 0; n < 4; ++n)
          acc[m][n] = __builtin_amdgcn_mfma_f32_16x16x32_bf16(af[m][0], bfr[n], z4, 0, 0, 0);
    }
#pragma unroll
    for (int kk = 1; kk < 4; ++kk) {
      bf16x8 bfr[4];
#pragma unroll
      for (int n = 0; n < 4; ++n)
        bfr[n] = *(const bf16x8*)(cur + (n * 16 + lr) * 256 + (((kk * 4 + lg) ^ lr) << 4));
#pragma unroll
      for (int m = 0; m < 2; ++m)
#pragma unroll
        for (int n = 0; n < 4; ++n)
          acc[m][n] = __builtin_amdgcn_mfma_f32_16x16x32_bf16(af[m][kk], bfr[n], acc[m][n], 0, 0, 0);
    }

    // exp + accumulate. C/D: col = lane&15, row(within m-frag) = lg*4 + reg.
    if (!between) {
#pragma unroll
      for (int m = 0; m < 2; ++m)
#pragma unroll
        for (int n = 0; n < 4; ++n)
#pragma unroll
          for (int r = 0; r < 4; ++r) rowp[m][r] += exp2f(acc[m][n][r]);
    } else {
      float colp[4];
#pragma unroll
      for (int n = 0; n < 4; ++n) colp[n] = 0.f;
#pragma unroll
      for (int m = 0; m < 2; ++m)
#pragma unroll
        for (int n = 0; n < 4; ++n) {
          float v0 = exp2f(acc[m][n][0]), v1 = exp2f(acc[m][n][1]);
          float v2 = exp2f(acc[m][n][2]), v3 = exp2f(acc[m][n][3]);
          rowp[m][0] += v0;
          rowp[m][1] += v1;
          rowp[m][2] += v2;
          rowp[m][3] += v3;
          colp[n] += (v0 + v1) + (v2 + v3);
        }
#pragma unroll
      for (int n = 0; n < 4; ++n) {  // reduce over lane-groups (rows); lanes l<16 hold cols
        float c = colp[n];
        c += __shfl_xor(c, 16);
        c += __shfl_xor(c, 32);
        if (l < 16) atomicAdd(&colBet[(j0 + t) * 64 + n * 16 + l], c);
      }
    }
  }

  // ---- deferred row reduction: shuffle over lr, one atomic per row ----
  float* rowdst = between ? rowBet : rowRefl;
#pragma unroll
  for (int m = 0; m < 2; ++m)
#pragma unroll
    for (int r = 0; r < 4; ++r) {
      float s = rowp[m][r];
      s += __shfl_xor(s, 1);
      s += __shfl_xor(s, 2);
      s += __shfl_xor(s, 4);
      s += __shfl_xor(s, 8);
      if (lr == 0) atomicAdd(&rowdst[bi * 128 + w * 32 + m * 16 + lg * 4 + r], s);
    }
}

// ---------- per-row loss (exact fp32 diagonals) ----------
__global__ void row_loss_kernel(const float* __restrict__ z1, const float* __restrict__ z2,
                                const float* __restrict__ rowRefl, const float* __restrict__ rowBet,
                                const float* __restrict__ colBet, float* __restrict__ rowLoss) {
  int gt = blockIdx.x * blockDim.x + threadIdx.x;
  int w = gt >> 6;  // one wave per row
  int l = threadIdx.x & 63;
  if (w >= N) return;
  float a0 = z1[w * D + l], a1 = z1[w * D + 64 + l];
  float b0 = z2[w * D + l], b1 = z2[w * D + 64 + l];
  float d11 = a0 * a0 + a1 * a1;  // |z1_i|^2
  float d12 = a0 * b0 + a1 * b1;  // z1_i . z2_i
#pragma unroll
  for (int mask = 1; mask < 64; mask <<= 1) {
    d11 += __shfl_xor(d11, mask);
    d12 += __shfl_xor(d12, mask);
  }
  if (l == 0) {
    float rdiag = exp2f(d11 * CEXP);  // exp(|z1_i|^2 / tau), exact fp32
    float denom1 = rowRefl[w] - rdiag + rowBet[w];
    float denom2 = rowRefl[w] - rdiag + colBet[w];
    // -log(pos) = -d12/tau = -2*d12 exactly (no exp/log roundtrip)
    rowLoss[w] = 0.5f * (logf(denom1) + logf(denom2)) - 2.0f * d12;
  }
}

__global__ void final_reduce_kernel(const float* __restrict__ rowLoss, float* __restrict__ out) {
  int g = blockIdx.x * 256 + threadIdx.x;  // grid: 32 blocks x 256 = 8192
  float s = rowLoss[g] * (1.0f / (float)N);
#pragma unroll
  for (int mask = 1; mask < 64; mask <<= 1) s += __shfl_xor(s, mask);
  if ((threadIdx.x & 63) == 0) atomicAdd(out, s);
}

extern "C" void kernel_launch(void* const* d_in, const int* in_sizes, int n_in,
                              void* d_out, int out_size, void* d_ws, size_t ws_size,
                              hipStream_t stream) {
  const float* z1 = (const float*)d_in[0];
  const float* z2 = (const float*)d_in[1];
  float* out = (float*)d_out;
  char* ws = (char*)d_ws;

  // ws: z1b(2MB) | z2b(2MB) | rowRefl(N) | rowBet(N) | colBet(N) | rowLoss(N)  (= round-2 footprint)
  u16* z1b = (u16*)ws;
  u16* z2b = (u16*)(ws + (size_t)N * D * 2);
  float* rowRefl = (float*)(ws + (size_t)2 * N * D * 2);
  float* rowBet = rowRefl + N;
  float* colBet = rowBet + N;
  float* rowLoss = colBet + N;

  convert_kernel<<<(N * D / 4) / 256, 256, 0, stream>>>((const float4*)z1, (const float4*)z2,
                                                        (uint2*)z1b, (uint2*)z2b);
  zero_kernel<<<(3 * N) / 256, 256, 0, stream>>>(rowRefl, out);  // rowRefl|rowBet|colBet + out
  gemm_kernel<<<1024, 256, 0, stream>>>(z1b, z2b, rowRefl, rowBet, colBet);
  row_loss_kernel<<<(N * 64) / 256, 256, 0, stream>>>(z1, z2, rowRefl, rowBet, colBet, rowLoss);
  final_reduce_kernel<<<32, 256, 0, stream>>>(rowLoss, out);
}